// Round 1
// baseline (1383.945 us; speedup 1.0000x reference)
//
#include <hip/hip_runtime.h>
#include <math.h>

#define NN 50000
#define NE 800000
#define NEP (NE + NN)   /* edges + self loops */
#define NG 128

__device__ __forceinline__ float lrelu02(float v) {
  return fmaxf(v, 0.0f) + 0.2f * fminf(v, 0.0f);
}
__device__ __forceinline__ float eluf(float v) {
  return v > 0.0f ? v : expm1f(v);
}

__global__ __launch_bounds__(256) void k_deg(const int* __restrict__ ei, int* __restrict__ deg) {
  int t = blockIdx.x * 256 + threadIdx.x;
  if (t >= NEP) return;
  int dst = (t < NE) ? ei[NE + t] : (t - NE);
  atomicAdd(&deg[dst], 1);
}

__global__ __launch_bounds__(1024) void k_scan(const int* __restrict__ deg, int* __restrict__ rowptr) {
  __shared__ int part[1024];
  int t = threadIdx.x;
  const int CH = (NN + 1023) >> 10;          // 49
  int b = t * CH;
  int e = min(b + CH, NN);
  int s = 0;
  for (int i = b; i < e; ++i) s += deg[i];
  part[t] = s;
  __syncthreads();
  for (int off = 1; off < 1024; off <<= 1) {
    int v = (t >= off) ? part[t - off] : 0;
    __syncthreads();
    part[t] += v;
    __syncthreads();
  }
  int run = (t == 0) ? 0 : part[t - 1];
  for (int i = b; i < e; ++i) { rowptr[i] = run; run += deg[i]; }
  if (t == 1023) rowptr[NN] = part[1023];
}

__global__ __launch_bounds__(256) void k_scatter(const int* __restrict__ ei, const int* __restrict__ rowptr,
                                                 int* __restrict__ fill, int* __restrict__ srcidx,
                                                 int* __restrict__ dstidx) {
  int t = blockIdx.x * 256 + threadIdx.x;
  if (t >= NEP) return;
  int src, dst;
  if (t < NE) { src = ei[t]; dst = ei[NE + t]; } else { src = t - NE; dst = src; }
  int pos = atomicAdd(&fill[dst], 1);
  int slot = rowptr[dst] + pos;
  srcidx[slot] = src;
  dstidx[slot] = dst;
}

// Y[row][col] = sum_k X[row][k] * W[col][k] + bias[col];  block = 32 rows x 64 cols
template <int DIN>
__global__ __launch_bounds__(256) void k_gemm(const float* __restrict__ X, const float* __restrict__ W,
                                              const float* __restrict__ bias, float* __restrict__ Y, int dout) {
  constexpr int K4 = DIN / 4;
  __shared__ float4 xs[32][K4];
  __shared__ float4 wt[K4][64];
  int t = threadIdx.x;
  int row0 = blockIdx.x * 32;
  int col0 = blockIdx.y * 64;
  for (int s = t; s < 64 * K4; s += 256) {
    int k4 = s >> 6, c = s & 63;
    wt[k4][c] = ((const float4*)(W + (size_t)(col0 + c) * DIN))[k4];
  }
  for (int s = t; s < 32 * K4; s += 256) {
    int r = s / K4, k4 = s % K4;
    int row = row0 + r;
    float4 v = {0.f, 0.f, 0.f, 0.f};
    if (row < NN) v = ((const float4*)(X + (size_t)row * DIN))[k4];
    xs[r][k4] = v;
  }
  __syncthreads();
  int c = t & 63;
  int rg = t >> 6;
  float acc[8] = {0.f,0.f,0.f,0.f,0.f,0.f,0.f,0.f};
  for (int k4 = 0; k4 < K4; ++k4) {
    float4 w4 = wt[k4][c];
#pragma unroll
    for (int r = 0; r < 8; ++r) {
      float4 xv = xs[rg * 8 + r][k4];
      acc[r] += xv.x * w4.x + xv.y * w4.y + xv.z * w4.z + xv.w * w4.w;
    }
  }
  float b = bias[col0 + c];
#pragma unroll
  for (int r = 0; r < 8; ++r) {
    int row = row0 + rg * 8 + r;
    if (row < NN) Y[(size_t)row * dout + col0 + c] = acc[r] + b;
  }
}

// one thread per (slot, head): s[slot][h] = sum_c lrelu(xl[src][h*C+c]+xr[dst][h*C+c]) * att[h][c]
template <int C>
__global__ __launch_bounds__(256) void k_score(const int* __restrict__ srcidx, const int* __restrict__ dstidx,
                                               const float* __restrict__ xl, const float* __restrict__ xr,
                                               const float* __restrict__ att, float* __restrict__ scores) {
  constexpr int D = 4 * C;
  int t = blockIdx.x * 256 + threadIdx.x;
  int slot = t >> 2, h = t & 3;
  if (slot >= NEP) return;
  int j = srcidx[slot], i = dstidx[slot];
  const float4* a = (const float4*)(xl + (size_t)j * D + h * C);
  const float4* b = (const float4*)(xr + (size_t)i * D + h * C);
  const float4* av = (const float4*)(att + h * C);
  float s = 0.f;
#pragma unroll
  for (int c4 = 0; c4 < C / 4; ++c4) {
    float4 x1 = a[c4], x2 = b[c4], aa = av[c4];
    s += lrelu02(x1.x + x2.x) * aa.x;
    s += lrelu02(x1.y + x2.y) * aa.y;
    s += lrelu02(x1.z + x2.z) * aa.z;
    s += lrelu02(x1.w + x2.w) * aa.w;
  }
  scores[slot * 4 + h] = s;
}

// wave per node: softmax over incoming slots + weighted aggregation + bias + ELU
template <int D, int C>
__global__ __launch_bounds__(256) void k_aggregate(const int* __restrict__ rowptr, const int* __restrict__ srcidx,
                                                   const float* __restrict__ scores, const float* __restrict__ xl,
                                                   const float* __restrict__ bias, float* __restrict__ out) {
  constexpr int V = D / 64;   // channels per lane (2 or 4)
  int lane = threadIdx.x & 63;
  int node = blockIdx.x * 4 + (threadIdx.x >> 6);
  if (node >= NN) return;
  int lo = rowptr[node], hi = rowptr[node + 1];
  const float4* sc4 = (const float4*)scores;

  float4 m = {-INFINITY, -INFINITY, -INFINITY, -INFINITY};
  for (int s = lo + lane; s < hi; s += 64) {
    float4 v = sc4[s];
    m.x = fmaxf(m.x, v.x); m.y = fmaxf(m.y, v.y);
    m.z = fmaxf(m.z, v.z); m.w = fmaxf(m.w, v.w);
  }
#pragma unroll
  for (int off = 32; off > 0; off >>= 1) {
    m.x = fmaxf(m.x, __shfl_xor(m.x, off));
    m.y = fmaxf(m.y, __shfl_xor(m.y, off));
    m.z = fmaxf(m.z, __shfl_xor(m.z, off));
    m.w = fmaxf(m.w, __shfl_xor(m.w, off));
  }
  float4 dsum = {0.f, 0.f, 0.f, 0.f};
  for (int s = lo + lane; s < hi; s += 64) {
    float4 v = sc4[s];
    dsum.x += expf(v.x - m.x); dsum.y += expf(v.y - m.y);
    dsum.z += expf(v.z - m.z); dsum.w += expf(v.w - m.w);
  }
#pragma unroll
  for (int off = 32; off > 0; off >>= 1) {
    dsum.x += __shfl_xor(dsum.x, off);
    dsum.y += __shfl_xor(dsum.y, off);
    dsum.z += __shfl_xor(dsum.z, off);
    dsum.w += __shfl_xor(dsum.w, off);
  }
  int head = lane >> 4;   // C/V = 16 lanes per head for both layers
  float mh  = (head & 2) ? ((head & 1) ? m.w : m.z) : ((head & 1) ? m.y : m.x);
  float dh  = (head & 2) ? ((head & 1) ? dsum.w : dsum.z) : ((head & 1) ? dsum.y : dsum.x);
  float rdh = 1.0f / dh;

  float acc[V] = {};
  for (int s = lo; s < hi; ++s) {
    float4 v = sc4[s];
    float sh = (head & 2) ? ((head & 1) ? v.w : v.z) : ((head & 1) ? v.y : v.x);
    float alpha = expf(sh - mh) * rdh;
    int j = srcidx[s];
    if (V == 2) {
      float2 xv = *(const float2*)(xl + (size_t)j * D + lane * 2);
      acc[0] += alpha * xv.x; acc[1] += alpha * xv.y;
    } else {
      float4 xv = *(const float4*)(xl + (size_t)j * D + lane * 4);
      acc[0] += alpha * xv.x; acc[1] += alpha * xv.y;
      acc[2] += alpha * xv.z; acc[3] += alpha * xv.w;
    }
  }
#pragma unroll
  for (int q = 0; q < V; ++q) {
    int ch = lane * V + q;
    out[(size_t)node * D + ch] = eluf(acc[q] + bias[ch]);
  }
}

__device__ __forceinline__ int lowerb(const int* __restrict__ a, int n, int v) {
  int lo = 0, hi = n;
  while (lo < hi) { int mid = (lo + hi) >> 1; if (a[mid] < v) lo = mid + 1; else hi = mid; }
  return lo;
}

__global__ __launch_bounds__(256) void k_pool(const float* __restrict__ h2, const int* __restrict__ batch,
                                              float* __restrict__ pooled) {
  int g = blockIdx.x, t = threadIdx.x;
  int lo = lowerb(batch, NN, g);
  int hi = lowerb(batch, NN, g + 1);
  float acc = 0.f;
  for (int n = lo; n < hi; ++n) acc += h2[(size_t)n * 256 + t];
  float cnt = (float)(hi - lo);
  pooled[g * 256 + t] = acc / fmaxf(cnt, 1.0f);
}

__global__ __launch_bounds__(128) void k_cls(const float* __restrict__ pooled, const float* __restrict__ Wf1,
                                             const float* __restrict__ bf1, const float* __restrict__ Wf2,
                                             const float* __restrict__ bf2, float* __restrict__ out) {
  __shared__ float p[256];
  __shared__ float z[128];
  int g = blockIdx.x, t = threadIdx.x;
  p[t] = pooled[g * 256 + t];
  p[t + 128] = pooled[g * 256 + t + 128];
  __syncthreads();
  float a = bf1[t];
  const float* wr = Wf1 + (size_t)t * 256;
  for (int k = 0; k < 256; ++k) a += p[k] * wr[k];
  z[t] = fmaxf(a, 0.f);
  __syncthreads();
  if (t < 8) {
    float o = bf2[t];
    const float* w2 = Wf2 + t * 128;
    for (int k = 0; k < 128; ++k) o += z[k] * w2[k];
    out[g * 8 + t] = o;
  }
}

extern "C" void kernel_launch(void* const* d_in, const int* in_sizes, int n_in,
                              void* d_out, int out_size, void* d_ws, size_t ws_size,
                              hipStream_t stream) {
  const float* x     = (const float*)d_in[0];
  const int*   ei    = (const int*)d_in[1];
  const int*   batch = (const int*)d_in[2];
  const float* Wl1 = (const float*)d_in[3];
  const float* bl1 = (const float*)d_in[4];
  const float* Wr1 = (const float*)d_in[5];
  const float* br1 = (const float*)d_in[6];
  const float* att1  = (const float*)d_in[7];
  const float* bias1 = (const float*)d_in[8];
  const float* Wl2 = (const float*)d_in[9];
  const float* bl2 = (const float*)d_in[10];
  const float* Wr2 = (const float*)d_in[11];
  const float* br2 = (const float*)d_in[12];
  const float* att2  = (const float*)d_in[13];
  const float* bias2 = (const float*)d_in[14];
  const float* Wf1 = (const float*)d_in[15];
  const float* bf1 = (const float*)d_in[16];
  const float* Wf2 = (const float*)d_in[17];
  const float* bf2 = (const float*)d_in[18];
  float* out = (float*)d_out;

  char* w = (char*)d_ws;
  size_t off = 0;
  auto alloc = [&](size_t bytes) -> void* {
    void* p = w + off;
    off += (bytes + 255) & ~(size_t)255;
    return p;
  };
  int*   rowptr = (int*)alloc((NN + 1) * sizeof(int));
  int*   deg    = (int*)alloc(NN * sizeof(int));
  int*   fill   = (int*)alloc(NN * sizeof(int));
  int*   srcidx = (int*)alloc((size_t)NEP * sizeof(int));
  int*   dstidx = (int*)alloc((size_t)NEP * sizeof(int));
  float* scores = (float*)alloc((size_t)NEP * 4 * sizeof(float));
  float* bufA   = (float*)alloc((size_t)NN * 256 * sizeof(float));  // xl1 -> xl2
  float* bufB   = (float*)alloc((size_t)NN * 256 * sizeof(float));  // xr1 -> xr2 -> h2
  float* h1     = (float*)alloc((size_t)NN * 128 * sizeof(float));
  float* pooled = (float*)alloc((size_t)NG * 256 * sizeof(float));
  (void)ws_size; (void)in_sizes; (void)n_in; (void)out_size;

  hipMemsetAsync(deg, 0, NN * sizeof(int), stream);
  hipMemsetAsync(fill, 0, NN * sizeof(int), stream);

  const int EB = (NEP + 255) / 256;
  k_deg<<<EB, 256, 0, stream>>>(ei, deg);
  k_scan<<<1, 1024, 0, stream>>>(deg, rowptr);
  k_scatter<<<EB, 256, 0, stream>>>(ei, rowptr, fill, srcidx, dstidx);

  // ---- layer 1 (64 -> 4x32) ----
  dim3 g1((NN + 31) / 32, 2);
  k_gemm<64><<<g1, 256, 0, stream>>>(x, Wl1, bl1, bufA, 128);
  k_gemm<64><<<g1, 256, 0, stream>>>(x, Wr1, br1, bufB, 128);
  const int SB = (NEP * 4 + 255) / 256;
  k_score<32><<<SB, 256, 0, stream>>>(srcidx, dstidx, bufA, bufB, att1, scores);
  k_aggregate<128, 32><<<(NN + 3) / 4, 256, 0, stream>>>(rowptr, srcidx, scores, bufA, bias1, h1);

  // ---- layer 2 (128 -> 4x64) ----
  dim3 g2((NN + 31) / 32, 4);
  k_gemm<128><<<g2, 256, 0, stream>>>(h1, Wl2, bl2, bufA, 256);
  k_gemm<128><<<g2, 256, 0, stream>>>(h1, Wr2, br2, bufB, 256);
  k_score<64><<<SB, 256, 0, stream>>>(srcidx, dstidx, bufA, bufB, att2, scores);
  k_aggregate<256, 64><<<(NN + 3) / 4, 256, 0, stream>>>(rowptr, srcidx, scores, bufA, bias2, bufB);

  // ---- pool + classifier ----
  k_pool<<<NG, 256, 0, stream>>>(bufB, batch, pooled);
  k_cls<<<NG, 128, 0, stream>>>(pooled, Wf1, bf1, Wf2, bf2, out);
}

// Round 2
// 811.399 us; speedup vs baseline: 1.7056x; 1.7056x over previous
//
#include <hip/hip_runtime.h>
#include <math.h>

#define NN 50000
#define NE 800000
#define NEP (NE + NN)   /* edges + self loops */
#define NG 128

__device__ __forceinline__ float lrelu02(float v) {
  return fmaxf(v, 0.0f) + 0.2f * fminf(v, 0.0f);
}
__device__ __forceinline__ float eluf(float v) {
  return v > 0.0f ? v : expm1f(v);
}

__global__ __launch_bounds__(256) void k_deg(const int* __restrict__ ei, int* __restrict__ deg) {
  int t = blockIdx.x * 256 + threadIdx.x;
  if (t >= NEP) return;
  int dst = (t < NE) ? ei[NE + t] : (t - NE);
  atomicAdd(&deg[dst], 1);
}

__global__ __launch_bounds__(1024) void k_scan(const int* __restrict__ deg, int* __restrict__ rowptr) {
  __shared__ int part[1024];
  int t = threadIdx.x;
  const int CH = (NN + 1023) >> 10;          // 49
  int b = t * CH;
  int e = min(b + CH, NN);
  int s = 0;
  for (int i = b; i < e; ++i) s += deg[i];
  part[t] = s;
  __syncthreads();
  for (int off = 1; off < 1024; off <<= 1) {
    int v = (t >= off) ? part[t - off] : 0;
    __syncthreads();
    part[t] += v;
    __syncthreads();
  }
  int run = (t == 0) ? 0 : part[t - 1];
  for (int i = b; i < e; ++i) { rowptr[i] = run; run += deg[i]; }
  if (t == 1023) rowptr[NN] = part[1023];
}

__global__ __launch_bounds__(256) void k_scatter(const int* __restrict__ ei, const int* __restrict__ rowptr,
                                                 int* __restrict__ fill, int* __restrict__ srcidx) {
  int t = blockIdx.x * 256 + threadIdx.x;
  if (t >= NEP) return;
  int src, dst;
  if (t < NE) { src = ei[t]; dst = ei[NE + t]; } else { src = t - NE; dst = src; }
  int pos = atomicAdd(&fill[dst], 1);
  srcidx[rowptr[dst] + pos] = src;
}

// Y[row][col] = sum_k X[row][k] * W[col][k] + bias[col];  block = 32 rows x 64 cols
template <int DIN>
__global__ __launch_bounds__(256) void k_gemm(const float* __restrict__ X, const float* __restrict__ W,
                                              const float* __restrict__ bias, float* __restrict__ Y, int dout) {
  constexpr int K4 = DIN / 4;
  __shared__ float4 xs[32][K4];
  __shared__ float4 wt[K4][64];
  int t = threadIdx.x;
  int row0 = blockIdx.x * 32;
  int col0 = blockIdx.y * 64;
  for (int s = t; s < 64 * K4; s += 256) {
    int k4 = s >> 6, c = s & 63;
    wt[k4][c] = ((const float4*)(W + (size_t)(col0 + c) * DIN))[k4];
  }
  for (int s = t; s < 32 * K4; s += 256) {
    int r = s / K4, k4 = s % K4;
    int row = row0 + r;
    float4 v = {0.f, 0.f, 0.f, 0.f};
    if (row < NN) v = ((const float4*)(X + (size_t)row * DIN))[k4];
    xs[r][k4] = v;
  }
  __syncthreads();
  int c = t & 63;
  int rg = t >> 6;
  float acc[8] = {0.f,0.f,0.f,0.f,0.f,0.f,0.f,0.f};
  for (int k4 = 0; k4 < K4; ++k4) {
    float4 w4 = wt[k4][c];
#pragma unroll
    for (int r = 0; r < 8; ++r) {
      float4 xv = xs[rg * 8 + r][k4];
      acc[r] += xv.x * w4.x + xv.y * w4.y + xv.z * w4.z + xv.w * w4.w;
    }
  }
  float b = bias[col0 + c];
#pragma unroll
  for (int r = 0; r < 8; ++r) {
    int row = row0 + rg * 8 + r;
    if (row < NN) Y[(size_t)row * dout + col0 + c] = acc[r] + b;
  }
}

// ---- fused GATv2 edge-score + online-softmax + aggregation ----
// wave per dst node. lane l owns channels [l*V, l*V+V) (V = D/64); 16 lanes per head.
// single pass over incoming edges: gather xl[src] once, score via 16-lane shuffle
// reduce, flash-style running {max, denom, weighted acc}.
template <int D>
__global__ __launch_bounds__(256) void k_fused(const int* __restrict__ rowptr, const int* __restrict__ srcidx,
                                               const float* __restrict__ xl, const float* __restrict__ xr,
                                               const float* __restrict__ att, const float* __restrict__ bias,
                                               float* __restrict__ out) {
  constexpr int V = D / 64;   // 2 (layer1) or 4 (layer2)
  int lane = threadIdx.x & 63;
  int node = blockIdx.x * 4 + (threadIdx.x >> 6);
  if (node >= NN) return;
  int lo = rowptr[node], hi = rowptr[node + 1];

  float xrv[V], attv[V];
#pragma unroll
  for (int q = 0; q < V; ++q) {
    xrv[q]  = xr[(size_t)node * D + lane * V + q];
    attv[q] = att[lane * V + q];   // global channel == h*C + c == lane*V + q
  }

  float m = -INFINITY, denom = 0.f;
  float acc[V] = {};

  auto score_partial = [&](const float* xv) {
    float p = 0.f;
#pragma unroll
    for (int q = 0; q < V; ++q) p += attv[q] * lrelu02(xv[q] + xrv[q]);
    return p;
  };
  auto update = [&](float sh, const float* xv) {
    float mn = fmaxf(m, sh);
    float cor = __expf(m - mn);
    float w = __expf(sh - mn);
    denom = denom * cor + w;
#pragma unroll
    for (int q = 0; q < V; ++q) acc[q] = acc[q] * cor + w * xv[q];
    m = mn;
  };

  int s = lo;
  for (; s + 1 < hi; s += 2) {
    int j0 = srcidx[s], j1 = srcidx[s + 1];
    float xv0[V], xv1[V];
    if constexpr (V == 2) {
      float2 a = *(const float2*)(xl + (size_t)j0 * D + lane * 2);
      float2 b = *(const float2*)(xl + (size_t)j1 * D + lane * 2);
      xv0[0] = a.x; xv0[1] = a.y; xv1[0] = b.x; xv1[1] = b.y;
    } else {
      float4 a = *(const float4*)(xl + (size_t)j0 * D + lane * 4);
      float4 b = *(const float4*)(xl + (size_t)j1 * D + lane * 4);
      xv0[0] = a.x; xv0[1] = a.y; xv0[2] = a.z; xv0[3] = a.w;
      xv1[0] = b.x; xv1[1] = b.y; xv1[2] = b.z; xv1[3] = b.w;
    }
    float p0 = score_partial(xv0);
    float p1 = score_partial(xv1);
#pragma unroll
    for (int off = 1; off < 16; off <<= 1) {
      p0 += __shfl_xor(p0, off);
      p1 += __shfl_xor(p1, off);
    }
    update(p0, xv0);
    update(p1, xv1);
  }
  if (s < hi) {
    int j0 = srcidx[s];
    float xv0[V];
    if constexpr (V == 2) {
      float2 a = *(const float2*)(xl + (size_t)j0 * D + lane * 2);
      xv0[0] = a.x; xv0[1] = a.y;
    } else {
      float4 a = *(const float4*)(xl + (size_t)j0 * D + lane * 4);
      xv0[0] = a.x; xv0[1] = a.y; xv0[2] = a.z; xv0[3] = a.w;
    }
    float p0 = score_partial(xv0);
#pragma unroll
    for (int off = 1; off < 16; off <<= 1) p0 += __shfl_xor(p0, off);
    update(p0, xv0);
  }

  float rd = 1.0f / denom;
#pragma unroll
  for (int q = 0; q < V; ++q) {
    int ch = lane * V + q;
    out[(size_t)node * D + ch] = eluf(acc[q] * rd + bias[ch]);
  }
}

__device__ __forceinline__ int lowerb(const int* __restrict__ a, int n, int v) {
  int lo = 0, hi = n;
  while (lo < hi) { int mid = (lo + hi) >> 1; if (a[mid] < v) lo = mid + 1; else hi = mid; }
  return lo;
}

__global__ __launch_bounds__(256) void k_pool(const float* __restrict__ h2, const int* __restrict__ batch,
                                              float* __restrict__ pooled) {
  int g = blockIdx.x, t = threadIdx.x;
  int lo = lowerb(batch, NN, g);
  int hi = lowerb(batch, NN, g + 1);
  float acc = 0.f;
  for (int n = lo; n < hi; ++n) acc += h2[(size_t)n * 256 + t];
  float cnt = (float)(hi - lo);
  pooled[g * 256 + t] = acc / fmaxf(cnt, 1.0f);
}

__global__ __launch_bounds__(128) void k_cls(const float* __restrict__ pooled, const float* __restrict__ Wf1,
                                             const float* __restrict__ bf1, const float* __restrict__ Wf2,
                                             const float* __restrict__ bf2, float* __restrict__ out) {
  __shared__ float p[256];
  __shared__ float z[128];
  int g = blockIdx.x, t = threadIdx.x;
  p[t] = pooled[g * 256 + t];
  p[t + 128] = pooled[g * 256 + t + 128];
  __syncthreads();
  float a = bf1[t];
  const float* wr = Wf1 + (size_t)t * 256;
  for (int k = 0; k < 256; ++k) a += p[k] * wr[k];
  z[t] = fmaxf(a, 0.f);
  __syncthreads();
  if (t < 8) {
    float o = bf2[t];
    const float* w2 = Wf2 + t * 128;
    for (int k = 0; k < 128; ++k) o += z[k] * w2[k];
    out[g * 8 + t] = o;
  }
}

extern "C" void kernel_launch(void* const* d_in, const int* in_sizes, int n_in,
                              void* d_out, int out_size, void* d_ws, size_t ws_size,
                              hipStream_t stream) {
  const float* x     = (const float*)d_in[0];
  const int*   ei    = (const int*)d_in[1];
  const int*   batch = (const int*)d_in[2];
  const float* Wl1 = (const float*)d_in[3];
  const float* bl1 = (const float*)d_in[4];
  const float* Wr1 = (const float*)d_in[5];
  const float* br1 = (const float*)d_in[6];
  const float* att1  = (const float*)d_in[7];
  const float* bias1 = (const float*)d_in[8];
  const float* Wl2 = (const float*)d_in[9];
  const float* bl2 = (const float*)d_in[10];
  const float* Wr2 = (const float*)d_in[11];
  const float* br2 = (const float*)d_in[12];
  const float* att2  = (const float*)d_in[13];
  const float* bias2 = (const float*)d_in[14];
  const float* Wf1 = (const float*)d_in[15];
  const float* bf1 = (const float*)d_in[16];
  const float* Wf2 = (const float*)d_in[17];
  const float* bf2 = (const float*)d_in[18];
  float* out = (float*)d_out;

  char* w = (char*)d_ws;
  size_t off = 0;
  auto alloc = [&](size_t bytes) -> void* {
    void* p = w + off;
    off += (bytes + 255) & ~(size_t)255;
    return p;
  };
  int*   rowptr = (int*)alloc((NN + 1) * sizeof(int));
  int*   deg    = (int*)alloc(NN * sizeof(int));
  int*   fill   = (int*)alloc(NN * sizeof(int));
  int*   srcidx = (int*)alloc((size_t)NEP * sizeof(int));
  float* bufA   = (float*)alloc((size_t)NN * 256 * sizeof(float));  // xl1 -> xl2
  float* bufB   = (float*)alloc((size_t)NN * 256 * sizeof(float));  // xr1 -> xr2 -> h2
  float* h1     = (float*)alloc((size_t)NN * 128 * sizeof(float));
  float* pooled = (float*)alloc((size_t)NG * 256 * sizeof(float));
  (void)ws_size; (void)in_sizes; (void)n_in; (void)out_size;

  hipMemsetAsync(deg, 0, NN * sizeof(int), stream);
  hipMemsetAsync(fill, 0, NN * sizeof(int), stream);

  const int EB = (NEP + 255) / 256;
  k_deg<<<EB, 256, 0, stream>>>(ei, deg);
  k_scan<<<1, 1024, 0, stream>>>(deg, rowptr);
  k_scatter<<<EB, 256, 0, stream>>>(ei, rowptr, fill, srcidx);

  // ---- layer 1 (64 -> 4x32) ----
  dim3 g1((NN + 31) / 32, 2);
  k_gemm<64><<<g1, 256, 0, stream>>>(x, Wl1, bl1, bufA, 128);
  k_gemm<64><<<g1, 256, 0, stream>>>(x, Wr1, br1, bufB, 128);
  k_fused<128><<<(NN + 3) / 4, 256, 0, stream>>>(rowptr, srcidx, bufA, bufB, att1, bias1, h1);

  // ---- layer 2 (128 -> 4x64) ----
  dim3 g2((NN + 31) / 32, 4);
  k_gemm<128><<<g2, 256, 0, stream>>>(h1, Wl2, bl2, bufA, 256);
  k_gemm<128><<<g2, 256, 0, stream>>>(h1, Wr2, br2, bufB, 256);
  k_fused<256><<<(NN + 3) / 4, 256, 0, stream>>>(rowptr, srcidx, bufA, bufB, att2, bias2, bufB);

  // ---- pool + classifier ----
  k_pool<<<NG, 256, 0, stream>>>(bufB, batch, pooled);
  k_cls<<<NG, 128, 0, stream>>>(pooled, Wf1, bf1, Wf2, bf2, out);
}